// Round 7
// baseline (758.382 us; speedup 1.0000x reference)
//
#include <hip/hip_runtime.h>

#define N_NODES 100000
#define N_EDGES 1600000
#define N_GRAPHS 1024
#define BN_EPS 1e-5f
#define BSH 6
#define BNODES 64            // nodes per bucket = 1<<BSH
#define NBUCK 1563           // ceil(100000/64)

// ================= bucketed CSR build (dst -> list of src) =================
// Stage 1: bucket histogram, LDS-aggregated (128 blocks grid-stride)
__global__ __launch_bounds__(256) void bhist_kernel(const int* __restrict__ dst,
                                                    int* __restrict__ bcnt) {
    __shared__ int lh[NBUCK];
    for (int i = threadIdx.x; i < NBUCK; i += 256) lh[i] = 0;
    __syncthreads();
    for (int e = blockIdx.x * 256 + threadIdx.x; e < N_EDGES; e += 128 * 256)
        atomicAdd(&lh[dst[e] >> BSH], 1);
    __syncthreads();
    for (int i = threadIdx.x; i < NBUCK; i += 256) {
        int v = lh[i];
        if (v) atomicAdd(&bcnt[i], v);
    }
}

// Stage 2: exclusive scan over 1563 bucket counts (one block, 2/thread)
__global__ __launch_bounds__(1024) void bscan_kernel(const int* __restrict__ bcnt,
                                                     int* __restrict__ bptr,
                                                     int* __restrict__ bcur) {
    __shared__ int ts[1024];
    int base = threadIdx.x * 2;
    int c0 = (base < NBUCK) ? bcnt[base] : 0;
    int c1 = (base + 1 < NBUCK) ? bcnt[base + 1] : 0;
    int s = c0 + c1;
    ts[threadIdx.x] = s;
    __syncthreads();
    for (int off = 1; off < 1024; off <<= 1) {
        int v = (threadIdx.x >= off) ? ts[threadIdx.x - off] : 0;
        __syncthreads();
        ts[threadIdx.x] += v;
        __syncthreads();
    }
    int run = ts[threadIdx.x] - s;
    if (base < NBUCK) { bptr[base] = run; bcur[base] = run; }
    if (base + 1 < NBUCK) { bptr[base + 1] = run + c0; bcur[base + 1] = run + c0; }
    if (threadIdx.x == 1023) bptr[NBUCK] = ts[1023];
}

// Stage 3: distribute (src,dst) pairs into bucket regions.
// Write frontier = 1563 lines (~100 KB) stays hot in L2 -> full-line useful writebacks.
__global__ __launch_bounds__(256) void bin_edges(const int* __restrict__ src,
                                                 const int* __restrict__ dst,
                                                 int* __restrict__ bcur,
                                                 int2* __restrict__ ebuf) {
    int e = blockIdx.x * 256 + threadIdx.x;
    if (e < N_EDGES) {
        int d = dst[e];
        int p = atomicAdd(&bcur[d >> BSH], 1);
        ebuf[p] = make_int2(src[e], d);
    }
}

// Stage 4: one block per bucket. LDS count -> LDS scan -> rowptr/cnt -> local scatter.
// All random traffic confined to the bucket's ~8KB region + 64 LDS counters.
__global__ __launch_bounds__(256) void bucket_csr(const int2* __restrict__ ebuf,
                                                  const int* __restrict__ bptr,
                                                  int* __restrict__ rowptr,
                                                  int* __restrict__ cnt,
                                                  int* __restrict__ elist) {
    int b = blockIdx.x;
    int rs = bptr[b], re = bptr[b + 1];
    int nbase = b << BSH;
    __shared__ int lcnt[BNODES], loff[BNODES];
    if (threadIdx.x < BNODES) lcnt[threadIdx.x] = 0;
    __syncthreads();
    for (int i = rs + threadIdx.x; i < re; i += 256)
        atomicAdd(&lcnt[ebuf[i].y & (BNODES - 1)], 1);
    __syncthreads();
    if (threadIdx.x < BNODES) loff[threadIdx.x] = lcnt[threadIdx.x];
    __syncthreads();
    for (int off = 1; off < BNODES; off <<= 1) {
        int v = 0;
        if (threadIdx.x < BNODES && threadIdx.x >= off) v = loff[threadIdx.x - off];
        __syncthreads();
        if (threadIdx.x < BNODES) loff[threadIdx.x] += v;
        __syncthreads();
    }
    if (threadIdx.x < BNODES) {
        loff[threadIdx.x] -= lcnt[threadIdx.x];  // exclusive
        int n = nbase + threadIdx.x;
        if (n < N_NODES) {
            rowptr[n] = rs + loff[threadIdx.x];
            cnt[n] = lcnt[threadIdx.x];
        }
    }
    __syncthreads();
    for (int i = rs + threadIdx.x; i < re; i += 256) {
        int2 e = ebuf[i];
        int p = atomicAdd(&loff[e.y & (BNODES - 1)], 1);
        elist[rs + p] = e.x;
    }
}

// ================= graph boundaries via binary search (batch is sorted) =================
__global__ __launch_bounds__(256) void gbounds(const int* __restrict__ batch,
                                               int* __restrict__ grow) {
    int g = blockIdx.x * 256 + threadIdx.x;
    if (g > N_GRAPHS) return;
    int lo = 0, hi = N_NODES;
    while (lo < hi) {
        int mid = (lo + hi) >> 1;
        if (batch[mid] < g) lo = mid + 1;
        else hi = mid;
    }
    grow[g] = lo;
}

// ================= aggregation by gather (no fp32 atomics) =================
// 8 lanes per node, one feature each (f<7); includes self term
__global__ __launch_bounds__(256) void gather7(const float* __restrict__ x,
                                               const int* __restrict__ rowptr,
                                               const int* __restrict__ cnt,
                                               const int* __restrict__ elist,
                                               float* __restrict__ agg) {
    int t = blockIdx.x * 256 + threadIdx.x;
    int n = t >> 3, f = t & 7;
    if (n >= N_NODES || f >= 7) return;
    int start = rowptr[n], k = cnt[n];
    float a = x[(size_t)n * 7 + f];
    for (int i = 0; i < k; i++) {
        int s = elist[start + i];
        a += x[(size_t)s * 7 + f];
    }
    agg[(size_t)n * 7 + f] = a;
}

// 16 lanes per node, float4 each; applies BN(scale/shift)+relu to every
// gathered row on the fly (relu precedes summation), includes self term
__global__ __launch_bounds__(256) void gather64_bn(const float* __restrict__ h2,
                                                   const float* __restrict__ ss,
                                                   const int* __restrict__ rowptr,
                                                   const int* __restrict__ cnt,
                                                   const int* __restrict__ elist,
                                                   float* __restrict__ agg) {
    int t = blockIdx.x * 256 + threadIdx.x;
    int n = t >> 4, c = t & 15;
    if (n >= N_NODES) return;
    float4 sc = ((const float4*)ss)[c];
    float4 sh = ((const float4*)(ss + 64))[c];
    int start = rowptr[n], k = cnt[n];
    const float4* h4 = (const float4*)h2;
    float4 v = h4[(size_t)n * 16 + c];
    float4 a;
    a.x = fmaxf(fmaf(v.x, sc.x, sh.x), 0.0f);
    a.y = fmaxf(fmaf(v.y, sc.y, sh.y), 0.0f);
    a.z = fmaxf(fmaf(v.z, sc.z, sh.z), 0.0f);
    a.w = fmaxf(fmaf(v.w, sc.w, sh.w), 0.0f);
    for (int i = 0; i < k; i++) {
        int s = elist[start + i];
        float4 w = h4[(size_t)s * 16 + c];
        a.x += fmaxf(fmaf(w.x, sc.x, sh.x), 0.0f);
        a.y += fmaxf(fmaf(w.y, sc.y, sh.y), 0.0f);
        a.z += fmaxf(fmaf(w.z, sc.z, sh.z), 0.0f);
        a.w += fmaxf(fmaf(w.w, sc.w, sh.w), 0.0f);
    }
    ((float4*)agg)[(size_t)n * 16 + c] = a;
}

// ================= MLP: h2 = relu(agg@w1+b1)@w2+b2 =================
template <int DIN>
__global__ __launch_bounds__(256) void mlp_kernel(const float* __restrict__ agg,
                                                  const float* __restrict__ w1,
                                                  const float* __restrict__ b1,
                                                  const float* __restrict__ w2,
                                                  const float* __restrict__ b2,
                                                  float* __restrict__ h2out) {
    int row = blockIdx.x * 256 + threadIdx.x;
    if (row >= N_NODES) return;
    const float* xr = agg + (size_t)row * DIN;

    float h1[64];
#pragma unroll
    for (int j = 0; j < 64; j++) h1[j] = b1[j];

    if constexpr (DIN == 7) {
#pragma unroll
        for (int k = 0; k < 7; k++) {
            float xv = xr[k];
#pragma unroll
            for (int j = 0; j < 64; j++) h1[j] = fmaf(xv, w1[k * 64 + j], h1[j]);
        }
    } else {
        const float4* xp = (const float4*)xr;
        for (int kk = 0; kk < DIN / 4; kk++) {
            float4 xv = xp[kk];
            const float* w = w1 + kk * 4 * 64;
#pragma unroll
            for (int j = 0; j < 64; j++) h1[j] = fmaf(xv.x, w[j], h1[j]);
#pragma unroll
            for (int j = 0; j < 64; j++) h1[j] = fmaf(xv.y, w[64 + j], h1[j]);
#pragma unroll
            for (int j = 0; j < 64; j++) h1[j] = fmaf(xv.z, w[128 + j], h1[j]);
#pragma unroll
            for (int j = 0; j < 64; j++) h1[j] = fmaf(xv.w, w[192 + j], h1[j]);
        }
    }
#pragma unroll
    for (int j = 0; j < 64; j++) h1[j] = fmaxf(h1[j], 0.0f);

    for (int j4 = 0; j4 < 16; j4++) {
        float4 o;
        float* ov = (float*)&o;
#pragma unroll
        for (int jj = 0; jj < 4; jj++) {
            int j = j4 * 4 + jj;
            float a = b2[j];
#pragma unroll
            for (int k = 0; k < 64; k++) a = fmaf(h1[k], w2[k * 64 + j], a);
            ov[jj] = a;
        }
        ((float4*)(h2out + (size_t)row * 64))[j4] = o;
    }
}

// ================= BN stats: per-feature sum / sumsq (fp64 accumulators) =================
__global__ __launch_bounds__(256) void bn_stats(const float* __restrict__ h2,
                                                double* __restrict__ acc) {
    long base = (long)blockIdx.x * 256 * 64;
    long end = base + 256L * 64;
    long lim = (long)N_NODES * 64;
    if (end > lim) end = lim;
    float s = 0.f, sq = 0.f;
    for (long i = base + threadIdx.x; i < end; i += 256) {
        float v = h2[i];
        s += v;
        sq += v * v;
    }
    __shared__ float ls[256], lq[256];
    ls[threadIdx.x] = s;
    lq[threadIdx.x] = sq;
    __syncthreads();
    if (threadIdx.x < 64) {
        float S = ls[threadIdx.x] + ls[threadIdx.x + 64] + ls[threadIdx.x + 128] + ls[threadIdx.x + 192];
        float Q = lq[threadIdx.x] + lq[threadIdx.x + 64] + lq[threadIdx.x + 128] + lq[threadIdx.x + 192];
        atomicAdd(&acc[threadIdx.x], (double)S);
        atomicAdd(&acc[64 + threadIdx.x], (double)Q);
    }
}

__global__ void bn_finalize(const double* __restrict__ acc, const float* __restrict__ gamma,
                            const float* __restrict__ beta, float* __restrict__ ss) {
    int j = threadIdx.x;
    if (j >= 64) return;
    double inv = 1.0 / (double)N_NODES;
    double mean = acc[j] * inv;
    double var = acc[64 + j] * inv - mean * mean;
    float scale = gamma[j] / sqrtf((float)var + BN_EPS);
    ss[j] = scale;
    ss[64 + j] = beta[j] - (float)mean * scale;
}

// ================= pool: BN+relu+mean over each graph's nodes (no atomics) =================
__global__ __launch_bounds__(256) void pool_bn(const float* __restrict__ h2,
                                               const float* __restrict__ ss,
                                               const int* __restrict__ grow,
                                               float* __restrict__ pooled) {
    int g = blockIdx.x;
    int start = grow[g], end = grow[g + 1];
    int c = threadIdx.x & 15, grp = threadIdx.x >> 4;
    float4 sc = ((const float4*)ss)[c];
    float4 sh = ((const float4*)(ss + 64))[c];
    const float4* h4 = (const float4*)h2;
    float4 a = {0.f, 0.f, 0.f, 0.f};
    for (int n = start + grp; n < end; n += 16) {
        float4 v = h4[(size_t)n * 16 + c];
        a.x += fmaxf(fmaf(v.x, sc.x, sh.x), 0.0f);
        a.y += fmaxf(fmaf(v.y, sc.y, sh.y), 0.0f);
        a.z += fmaxf(fmaf(v.z, sc.z, sh.z), 0.0f);
        a.w += fmaxf(fmaf(v.w, sc.w, sh.w), 0.0f);
    }
    __shared__ float4 ls[256];
    ls[threadIdx.x] = a;
    __syncthreads();
    for (int off = 128; off >= 16; off >>= 1) {
        if (threadIdx.x < off) {
            float4 b = ls[threadIdx.x + off];
            ls[threadIdx.x].x += b.x;
            ls[threadIdx.x].y += b.y;
            ls[threadIdx.x].z += b.z;
            ls[threadIdx.x].w += b.w;
        }
        __syncthreads();
    }
    if (threadIdx.x < 16) {
        float inv = 1.0f / fmaxf((float)(end - start), 1.0f);
        float4 r = ls[threadIdx.x];
        r.x *= inv; r.y *= inv; r.z *= inv; r.w *= inv;
        ((float4*)pooled)[(size_t)g * 16 + threadIdx.x] = r;
    }
}

// ================= final: proj + L2 normalize; one wave per graph =================
__global__ __launch_bounds__(256) void final_proj(const float* __restrict__ pooled,
                                                  const float* __restrict__ pw,
                                                  const float* __restrict__ pb,
                                                  float* __restrict__ out) {
    __shared__ float sw[64 * 64];
    for (int i = threadIdx.x; i < 4096; i += 256) sw[i] = pw[i];
    __syncthreads();
    int g = blockIdx.x * 4 + (threadIdx.x >> 6);
    int j = threadIdx.x & 63;
    if (g >= N_GRAPHS) return;
    float a = pb[j];
#pragma unroll
    for (int k = 0; k < 64; k++) a = fmaf(pooled[(size_t)g * 64 + k], sw[k * 64 + j], a);
    float ss2 = a * a;
#pragma unroll
    for (int off = 1; off < 64; off <<= 1) ss2 += __shfl_xor(ss2, off);
    out[(size_t)g * 64 + j] = a / fmaxf(sqrtf(ss2), 1e-12f);
}

extern "C" void kernel_launch(void* const* d_in, const int* in_sizes, int n_in,
                              void* d_out, int out_size, void* d_ws, size_t ws_size,
                              hipStream_t stream) {
    const float* x = (const float*)d_in[0];
    const int* eidx = (const int*)d_in[1];
    const int* batch = (const int*)d_in[2];
    const int* src = eidx;
    const int* dst = eidx + N_EDGES;
    const float* W1[3] = {(const float*)d_in[3], (const float*)d_in[9], (const float*)d_in[15]};
    const float* B1[3] = {(const float*)d_in[4], (const float*)d_in[10], (const float*)d_in[16]};
    const float* W2[3] = {(const float*)d_in[5], (const float*)d_in[11], (const float*)d_in[17]};
    const float* B2[3] = {(const float*)d_in[6], (const float*)d_in[12], (const float*)d_in[18]};
    const float* GM[3] = {(const float*)d_in[7], (const float*)d_in[13], (const float*)d_in[19]};
    const float* BT[3] = {(const float*)d_in[8], (const float*)d_in[14], (const float*)d_in[20]};
    const float* PW = (const float*)d_in[21];
    const float* PB = (const float*)d_in[22];
    float* out = (float*)d_out;

    char* ws = (char*)d_ws;
    size_t off = 0;
    auto alloc = [&](size_t bytes) -> void* {
        void* p = ws + off;
        off += (bytes + 255) & ~(size_t)255;
        return p;
    };
    float* A    = (float*)alloc((size_t)N_NODES * 64 * 4);  // h2 buffer
    float* C    = (float*)alloc((size_t)N_NODES * 64 * 4);  // agg buffer
    float* agg0 = (float*)alloc((size_t)N_NODES * 7 * 4);
    int* cnt    = (int*)alloc((size_t)N_NODES * 4);
    int* rowptr = (int*)alloc((size_t)N_NODES * 4);
    int* elist  = (int*)alloc((size_t)N_EDGES * 4);
    int2* ebuf  = (int2*)alloc((size_t)N_EDGES * 8);
    int* bcnt   = (int*)alloc((size_t)NBUCK * 4);
    int* bptr   = (int*)alloc((size_t)(NBUCK + 1) * 4);
    int* bcur   = (int*)alloc((size_t)NBUCK * 4);
    int* grow   = (int*)alloc(1025 * 4);
    double* acc = (double*)alloc(3 * 128 * sizeof(double));
    float* ss0    = (float*)alloc(128 * 4);
    float* ss1    = (float*)alloc(128 * 4);
    float* ss2    = (float*)alloc(128 * 4);
    float* pooled = (float*)alloc((size_t)N_GRAPHS * 64 * 4);

    hipMemsetAsync(bcnt, 0, (size_t)NBUCK * 4, stream);
    hipMemsetAsync(acc, 0, 3 * 128 * sizeof(double), stream);

    const int edge_grid = (N_EDGES + 255) / 256;       // 6250
    const int row_grid = (N_NODES + 255) / 256;        // 391
    const int vec_grid = (N_NODES * 16 + 255) / 256;   // 6250
    const int g7_grid = (N_NODES * 8 + 255) / 256;     // 3125

    // ---- bucketed CSR build (node-level, reused by all 3 layers) ----
    bhist_kernel<<<128, 256, 0, stream>>>(dst, bcnt);
    bscan_kernel<<<1, 1024, 0, stream>>>(bcnt, bptr, bcur);
    bin_edges<<<edge_grid, 256, 0, stream>>>(src, dst, bcur, ebuf);
    bucket_csr<<<NBUCK, 256, 0, stream>>>(ebuf, bptr, rowptr, cnt, elist);
    gbounds<<<5, 256, 0, stream>>>(batch, grow);

    // ---- layer 0 ----
    gather7<<<g7_grid, 256, 0, stream>>>(x, rowptr, cnt, elist, agg0);
    mlp_kernel<7><<<row_grid, 256, 0, stream>>>(agg0, W1[0], B1[0], W2[0], B2[0], A);
    bn_stats<<<row_grid, 256, 0, stream>>>(A, acc);
    bn_finalize<<<1, 64, 0, stream>>>(acc, GM[0], BT[0], ss0);

    // ---- layer 1 (BN+relu of layer 0 fused into gather) ----
    gather64_bn<<<vec_grid, 256, 0, stream>>>(A, ss0, rowptr, cnt, elist, C);
    mlp_kernel<64><<<row_grid, 256, 0, stream>>>(C, W1[1], B1[1], W2[1], B2[1], A);
    bn_stats<<<row_grid, 256, 0, stream>>>(A, acc + 128);
    bn_finalize<<<1, 64, 0, stream>>>(acc + 128, GM[1], BT[1], ss1);

    // ---- layer 2 ----
    gather64_bn<<<vec_grid, 256, 0, stream>>>(A, ss1, rowptr, cnt, elist, C);
    mlp_kernel<64><<<row_grid, 256, 0, stream>>>(C, W1[2], B1[2], W2[2], B2[2], A);
    bn_stats<<<row_grid, 256, 0, stream>>>(A, acc + 256);
    bn_finalize<<<1, 64, 0, stream>>>(acc + 256, GM[2], BT[2], ss2);

    // ---- pool (BN+relu fused, deterministic per-graph reduction) ----
    pool_bn<<<N_GRAPHS, 256, 0, stream>>>(A, ss2, grow, pooled);

    // ---- readout ----
    final_proj<<<N_GRAPHS / 4, 256, 0, stream>>>(pooled, PW, PB, out);
}

// Round 11
// 558.827 us; speedup vs baseline: 1.3571x; 1.3571x over previous
//
#include <hip/hip_runtime.h>

#define N_NODES 100000
#define N_EDGES 1600000
#define N_GRAPHS 1024
#define BN_EPS 1e-5f
#define BSH 6
#define BNODES 64            // nodes per bucket = 1<<BSH
#define NBUCK 1563           // ceil(100000/64)
#define NB 128               // multi-split blocks (chunks)
#define CH 12500             // edges per chunk = N_EDGES/NB
#define MS_N (NBUCK * NB)    // 200064 scan elements
#define MS_SBLK ((MS_N + 1023) / 1024)  // 196

// ================= deterministic multi-split CSR build (dst -> list of src) =================
// Pass A: per-chunk LDS histogram over 1563 buckets -> hist[bucket][block]
__global__ __launch_bounds__(256) void msplit_hist(const int* __restrict__ dst,
                                                   int* __restrict__ hist_g) {
    __shared__ int lh[NBUCK];
    for (int i = threadIdx.x; i < NBUCK; i += 256) lh[i] = 0;
    __syncthreads();
    int e0 = blockIdx.x * CH;
    int e1 = min(e0 + CH, N_EDGES);
    for (int e = e0 + threadIdx.x; e < e1; e += 256)
        atomicAdd(&lh[dst[e] >> BSH], 1);
    __syncthreads();
    for (int i = threadIdx.x; i < NBUCK; i += 256)
        hist_g[i * NB + blockIdx.x] = lh[i];
}

// Scan chain over MS_N entries (bucket-major) -> exact (bucket,block) bases
__global__ __launch_bounds__(256) void ms_scan_blocks(const int* __restrict__ in,
                                                      int* __restrict__ out,
                                                      int* __restrict__ bsum) {
    __shared__ int ts[256];
    int base = blockIdx.x * 1024 + threadIdx.x * 4;
    int c[4];
#pragma unroll
    for (int i = 0; i < 4; i++) {
        int idx = base + i;
        c[i] = (idx < MS_N) ? in[idx] : 0;
    }
    int s = c[0] + c[1] + c[2] + c[3];
    ts[threadIdx.x] = s;
    __syncthreads();
    for (int off = 1; off < 256; off <<= 1) {
        int v = (threadIdx.x >= off) ? ts[threadIdx.x - off] : 0;
        __syncthreads();
        ts[threadIdx.x] += v;
        __syncthreads();
    }
    int run = ts[threadIdx.x] - s;  // exclusive
#pragma unroll
    for (int i = 0; i < 4; i++) {
        int idx = base + i;
        if (idx < MS_N) out[idx] = run;
        run += c[i];
    }
    if (threadIdx.x == 255) bsum[blockIdx.x] = ts[255];
}

__global__ void ms_scan_sums(int* bsum) {
    if (threadIdx.x == 0) {
        int run = 0;
        for (int i = 0; i < MS_SBLK; i++) {
            int v = bsum[i];
            bsum[i] = run;
            run += v;
        }
    }
}

__global__ __launch_bounds__(256) void ms_scan_apply(int* __restrict__ data,
                                                     const int* __restrict__ bsum,
                                                     int* __restrict__ bptr) {
    int i = blockIdx.x * 256 + threadIdx.x;
    if (i < MS_N) {
        int v = data[i] + bsum[i >> 10];
        data[i] = v;
        if ((i & (NB - 1)) == 0) bptr[i / NB] = v;  // bucket base
    }
    if (i == 0) bptr[NBUCK] = N_EDGES;
}

// Pass B: place edges at base + LDS-rank. No global atomics; runs are ~line-sized.
// Packed payload: (dst&63)<<17 | src   (src < 2^17)
__global__ __launch_bounds__(256) void msplit_place(const int* __restrict__ src,
                                                    const int* __restrict__ dst,
                                                    const int* __restrict__ hist_s,
                                                    int* __restrict__ ebuf) {
    __shared__ int lbase[NBUCK];
    for (int i = threadIdx.x; i < NBUCK; i += 256)
        lbase[i] = hist_s[i * NB + blockIdx.x];
    __syncthreads();
    int e0 = blockIdx.x * CH;
    int e1 = min(e0 + CH, N_EDGES);
    for (int e = e0 + threadIdx.x; e < e1; e += 256) {
        int d = dst[e];
        int p = atomicAdd(&lbase[d >> BSH], 1);  // LDS atomic: unique rank
        ebuf[p] = ((d & (BNODES - 1)) << 17) | src[e];
    }
}

// Stage 4: one block per bucket. LDS count -> LDS scan -> rowptr/cnt -> local scatter.
__global__ __launch_bounds__(256) void bucket_csr(const int* __restrict__ ebuf,
                                                  const int* __restrict__ bptr,
                                                  int* __restrict__ rowptr,
                                                  int* __restrict__ cnt,
                                                  int* __restrict__ elist) {
    int b = blockIdx.x;
    int rs = bptr[b], re = bptr[b + 1];
    int nbase = b << BSH;
    __shared__ int lcnt[BNODES], loff[BNODES];
    if (threadIdx.x < BNODES) lcnt[threadIdx.x] = 0;
    __syncthreads();
    for (int i = rs + threadIdx.x; i < re; i += 256)
        atomicAdd(&lcnt[ebuf[i] >> 17], 1);
    __syncthreads();
    if (threadIdx.x < BNODES) loff[threadIdx.x] = lcnt[threadIdx.x];
    __syncthreads();
    for (int off = 1; off < BNODES; off <<= 1) {
        int v = 0;
        if (threadIdx.x < BNODES && threadIdx.x >= off) v = loff[threadIdx.x - off];
        __syncthreads();
        if (threadIdx.x < BNODES) loff[threadIdx.x] += v;
        __syncthreads();
    }
    if (threadIdx.x < BNODES) {
        loff[threadIdx.x] -= lcnt[threadIdx.x];  // exclusive
        int n = nbase + threadIdx.x;
        if (n < N_NODES) {
            rowptr[n] = rs + loff[threadIdx.x];
            cnt[n] = lcnt[threadIdx.x];
        }
    }
    __syncthreads();
    for (int i = rs + threadIdx.x; i < re; i += 256) {
        int pk = ebuf[i];
        int p = atomicAdd(&loff[pk >> 17], 1);
        elist[rs + p] = pk & 0x1FFFF;
    }
}

// ================= graph boundaries via binary search (batch is sorted) =================
__global__ __launch_bounds__(256) void gbounds(const int* __restrict__ batch,
                                               int* __restrict__ grow) {
    int g = blockIdx.x * 256 + threadIdx.x;
    if (g > N_GRAPHS) return;
    int lo = 0, hi = N_NODES;
    while (lo < hi) {
        int mid = (lo + hi) >> 1;
        if (batch[mid] < g) lo = mid + 1;
        else hi = mid;
    }
    grow[g] = lo;
}

// ================= aggregation by gather (no fp32 atomics) =================
__global__ __launch_bounds__(256) void gather7(const float* __restrict__ x,
                                               const int* __restrict__ rowptr,
                                               const int* __restrict__ cnt,
                                               const int* __restrict__ elist,
                                               float* __restrict__ agg) {
    int t = blockIdx.x * 256 + threadIdx.x;
    int n = t >> 3, f = t & 7;
    if (n >= N_NODES || f >= 7) return;
    int start = rowptr[n], k = cnt[n];
    float a = x[(size_t)n * 7 + f];
    for (int i = 0; i < k; i++) {
        int s = elist[start + i];
        a += x[(size_t)s * 7 + f];
    }
    agg[(size_t)n * 7 + f] = a;
}

// 16 lanes per node, float4 each; BN+relu applied on the fly; includes self term
__global__ __launch_bounds__(256) void gather64_bn(const float* __restrict__ h2,
                                                   const float* __restrict__ ss,
                                                   const int* __restrict__ rowptr,
                                                   const int* __restrict__ cnt,
                                                   const int* __restrict__ elist,
                                                   float* __restrict__ agg) {
    int t = blockIdx.x * 256 + threadIdx.x;
    int n = t >> 4, c = t & 15;
    if (n >= N_NODES) return;
    float4 sc = ((const float4*)ss)[c];
    float4 sh = ((const float4*)(ss + 64))[c];
    int start = rowptr[n], k = cnt[n];
    const float4* h4 = (const float4*)h2;
    float4 v = h4[(size_t)n * 16 + c];
    float4 a;
    a.x = fmaxf(fmaf(v.x, sc.x, sh.x), 0.0f);
    a.y = fmaxf(fmaf(v.y, sc.y, sh.y), 0.0f);
    a.z = fmaxf(fmaf(v.z, sc.z, sh.z), 0.0f);
    a.w = fmaxf(fmaf(v.w, sc.w, sh.w), 0.0f);
    for (int i = 0; i < k; i++) {
        int s = elist[start + i];
        float4 w = h4[(size_t)s * 16 + c];
        a.x += fmaxf(fmaf(w.x, sc.x, sh.x), 0.0f);
        a.y += fmaxf(fmaf(w.y, sc.y, sh.y), 0.0f);
        a.z += fmaxf(fmaf(w.z, sc.z, sh.z), 0.0f);
        a.w += fmaxf(fmaf(w.w, sc.w, sh.w), 0.0f);
    }
    ((float4*)agg)[(size_t)n * 16 + c] = a;
}

// ================= MLP: h2 = relu(agg@w1+b1)@w2+b2 =================
template <int DIN>
__global__ __launch_bounds__(256) void mlp_kernel(const float* __restrict__ agg,
                                                  const float* __restrict__ w1,
                                                  const float* __restrict__ b1,
                                                  const float* __restrict__ w2,
                                                  const float* __restrict__ b2,
                                                  float* __restrict__ h2out) {
    int row = blockIdx.x * 256 + threadIdx.x;
    if (row >= N_NODES) return;
    const float* xr = agg + (size_t)row * DIN;

    float h1[64];
#pragma unroll
    for (int j = 0; j < 64; j++) h1[j] = b1[j];

    if constexpr (DIN == 7) {
#pragma unroll
        for (int k = 0; k < 7; k++) {
            float xv = xr[k];
#pragma unroll
            for (int j = 0; j < 64; j++) h1[j] = fmaf(xv, w1[k * 64 + j], h1[j]);
        }
    } else {
        const float4* xp = (const float4*)xr;
        for (int kk = 0; kk < DIN / 4; kk++) {
            float4 xv = xp[kk];
            const float* w = w1 + kk * 4 * 64;
#pragma unroll
            for (int j = 0; j < 64; j++) h1[j] = fmaf(xv.x, w[j], h1[j]);
#pragma unroll
            for (int j = 0; j < 64; j++) h1[j] = fmaf(xv.y, w[64 + j], h1[j]);
#pragma unroll
            for (int j = 0; j < 64; j++) h1[j] = fmaf(xv.z, w[128 + j], h1[j]);
#pragma unroll
            for (int j = 0; j < 64; j++) h1[j] = fmaf(xv.w, w[192 + j], h1[j]);
        }
    }
#pragma unroll
    for (int j = 0; j < 64; j++) h1[j] = fmaxf(h1[j], 0.0f);

    for (int j4 = 0; j4 < 16; j4++) {
        float4 o;
        float* ov = (float*)&o;
#pragma unroll
        for (int jj = 0; jj < 4; jj++) {
            int j = j4 * 4 + jj;
            float a = b2[j];
#pragma unroll
            for (int k = 0; k < 64; k++) a = fmaf(h1[k], w2[k * 64 + j], a);
            ov[jj] = a;
        }
        ((float4*)(h2out + (size_t)row * 64))[j4] = o;
    }
}

// ================= BN stats: per-feature sum / sumsq (fp64 accumulators) =================
__global__ __launch_bounds__(256) void bn_stats(const float* __restrict__ h2,
                                                double* __restrict__ acc) {
    long base = (long)blockIdx.x * 256 * 64;
    long end = base + 256L * 64;
    long lim = (long)N_NODES * 64;
    if (end > lim) end = lim;
    float s = 0.f, sq = 0.f;
    for (long i = base + threadIdx.x; i < end; i += 256) {
        float v = h2[i];
        s += v;
        sq += v * v;
    }
    __shared__ float ls[256], lq[256];
    ls[threadIdx.x] = s;
    lq[threadIdx.x] = sq;
    __syncthreads();
    if (threadIdx.x < 64) {
        float S = ls[threadIdx.x] + ls[threadIdx.x + 64] + ls[threadIdx.x + 128] + ls[threadIdx.x + 192];
        float Q = lq[threadIdx.x] + lq[threadIdx.x + 64] + lq[threadIdx.x + 128] + lq[threadIdx.x + 192];
        atomicAdd(&acc[threadIdx.x], (double)S);
        atomicAdd(&acc[64 + threadIdx.x], (double)Q);
    }
}

__global__ void bn_finalize(const double* __restrict__ acc, const float* __restrict__ gamma,
                            const float* __restrict__ beta, float* __restrict__ ss) {
    int j = threadIdx.x;
    if (j >= 64) return;
    double inv = 1.0 / (double)N_NODES;
    double mean = acc[j] * inv;
    double var = acc[64 + j] * inv - mean * mean;
    float scale = gamma[j] / sqrtf((float)var + BN_EPS);
    ss[j] = scale;
    ss[64 + j] = beta[j] - (float)mean * scale;
}

// ================= pool: BN+relu+mean over each graph's nodes (no atomics) =================
__global__ __launch_bounds__(256) void pool_bn(const float* __restrict__ h2,
                                               const float* __restrict__ ss,
                                               const int* __restrict__ grow,
                                               float* __restrict__ pooled) {
    int g = blockIdx.x;
    int start = grow[g], end = grow[g + 1];
    int c = threadIdx.x & 15, grp = threadIdx.x >> 4;
    float4 sc = ((const float4*)ss)[c];
    float4 sh = ((const float4*)(ss + 64))[c];
    const float4* h4 = (const float4*)h2;
    float4 a = {0.f, 0.f, 0.f, 0.f};
    for (int n = start + grp; n < end; n += 16) {
        float4 v = h4[(size_t)n * 16 + c];
        a.x += fmaxf(fmaf(v.x, sc.x, sh.x), 0.0f);
        a.y += fmaxf(fmaf(v.y, sc.y, sh.y), 0.0f);
        a.z += fmaxf(fmaf(v.z, sc.z, sh.z), 0.0f);
        a.w += fmaxf(fmaf(v.w, sc.w, sh.w), 0.0f);
    }
    __shared__ float4 ls[256];
    ls[threadIdx.x] = a;
    __syncthreads();
    for (int off = 128; off >= 16; off >>= 1) {
        if (threadIdx.x < off) {
            float4 b = ls[threadIdx.x + off];
            ls[threadIdx.x].x += b.x;
            ls[threadIdx.x].y += b.y;
            ls[threadIdx.x].z += b.z;
            ls[threadIdx.x].w += b.w;
        }
        __syncthreads();
    }
    if (threadIdx.x < 16) {
        float inv = 1.0f / fmaxf((float)(end - start), 1.0f);
        float4 r = ls[threadIdx.x];
        r.x *= inv; r.y *= inv; r.z *= inv; r.w *= inv;
        ((float4*)pooled)[(size_t)g * 16 + threadIdx.x] = r;
    }
}

// ================= final: proj + L2 normalize; one wave per graph =================
__global__ __launch_bounds__(256) void final_proj(const float* __restrict__ pooled,
                                                  const float* __restrict__ pw,
                                                  const float* __restrict__ pb,
                                                  float* __restrict__ out) {
    __shared__ float sw[64 * 64];
    for (int i = threadIdx.x; i < 4096; i += 256) sw[i] = pw[i];
    __syncthreads();
    int g = blockIdx.x * 4 + (threadIdx.x >> 6);
    int j = threadIdx.x & 63;
    if (g >= N_GRAPHS) return;
    float a = pb[j];
#pragma unroll
    for (int k = 0; k < 64; k++) a = fmaf(pooled[(size_t)g * 64 + k], sw[k * 64 + j], a);
    float ss2 = a * a;
#pragma unroll
    for (int off = 1; off < 64; off <<= 1) ss2 += __shfl_xor(ss2, off);
    out[(size_t)g * 64 + j] = a / fmaxf(sqrtf(ss2), 1e-12f);
}

extern "C" void kernel_launch(void* const* d_in, const int* in_sizes, int n_in,
                              void* d_out, int out_size, void* d_ws, size_t ws_size,
                              hipStream_t stream) {
    const float* x = (const float*)d_in[0];
    const int* eidx = (const int*)d_in[1];
    const int* batch = (const int*)d_in[2];
    const int* src = eidx;
    const int* dst = eidx + N_EDGES;
    const float* W1[3] = {(const float*)d_in[3], (const float*)d_in[9], (const float*)d_in[15]};
    const float* B1[3] = {(const float*)d_in[4], (const float*)d_in[10], (const float*)d_in[16]};
    const float* W2[3] = {(const float*)d_in[5], (const float*)d_in[11], (const float*)d_in[17]};
    const float* B2[3] = {(const float*)d_in[6], (const float*)d_in[12], (const float*)d_in[18]};
    const float* GM[3] = {(const float*)d_in[7], (const float*)d_in[13], (const float*)d_in[19]};
    const float* BT[3] = {(const float*)d_in[8], (const float*)d_in[14], (const float*)d_in[20]};
    const float* PW = (const float*)d_in[21];
    const float* PB = (const float*)d_in[22];
    float* out = (float*)d_out;

    char* ws = (char*)d_ws;
    size_t off = 0;
    auto alloc = [&](size_t bytes) -> void* {
        void* p = ws + off;
        off += (bytes + 255) & ~(size_t)255;
        return p;
    };
    float* A    = (float*)alloc((size_t)N_NODES * 64 * 4);  // h2 buffer
    float* C    = (float*)alloc((size_t)N_NODES * 64 * 4);  // agg buffer
    float* agg0 = (float*)alloc((size_t)N_NODES * 7 * 4);
    int* cnt    = (int*)alloc((size_t)N_NODES * 4);
    int* rowptr = (int*)alloc((size_t)N_NODES * 4);
    int* elist  = (int*)alloc((size_t)N_EDGES * 4);
    int* ebuf   = (int*)alloc((size_t)N_EDGES * 4);   // packed (dlo<<17)|src
    int* hist_g = (int*)alloc((size_t)MS_N * 4);
    int* hist_s = (int*)alloc((size_t)MS_N * 4);
    int* msum   = (int*)alloc((size_t)MS_SBLK * 4);
    int* bptr   = (int*)alloc((size_t)(NBUCK + 1) * 4);
    int* grow   = (int*)alloc(1025 * 4);
    double* acc = (double*)alloc(3 * 128 * sizeof(double));
    float* ss0    = (float*)alloc(128 * 4);
    float* ss1    = (float*)alloc(128 * 4);
    float* ss2    = (float*)alloc(128 * 4);
    float* pooled = (float*)alloc((size_t)N_GRAPHS * 64 * 4);

    hipMemsetAsync(acc, 0, 3 * 128 * sizeof(double), stream);

    const int row_grid = (N_NODES + 255) / 256;        // 391
    const int vec_grid = (N_NODES * 16 + 255) / 256;   // 6250
    const int g7_grid = (N_NODES * 8 + 255) / 256;     // 3125

    // ---- deterministic multi-split CSR build (reused by all 3 layers) ----
    msplit_hist<<<NB, 256, 0, stream>>>(dst, hist_g);
    ms_scan_blocks<<<MS_SBLK, 256, 0, stream>>>(hist_g, hist_s, msum);
    ms_scan_sums<<<1, 64, 0, stream>>>(msum);
    ms_scan_apply<<<(MS_N + 255) / 256, 256, 0, stream>>>(hist_s, msum, bptr);
    msplit_place<<<NB, 256, 0, stream>>>(src, dst, hist_s, ebuf);
    bucket_csr<<<NBUCK, 256, 0, stream>>>(ebuf, bptr, rowptr, cnt, elist);
    gbounds<<<5, 256, 0, stream>>>(batch, grow);

    // ---- layer 0 ----
    gather7<<<g7_grid, 256, 0, stream>>>(x, rowptr, cnt, elist, agg0);
    mlp_kernel<7><<<row_grid, 256, 0, stream>>>(agg0, W1[0], B1[0], W2[0], B2[0], A);
    bn_stats<<<row_grid, 256, 0, stream>>>(A, acc);
    bn_finalize<<<1, 64, 0, stream>>>(acc, GM[0], BT[0], ss0);

    // ---- layer 1 (BN+relu of layer 0 fused into gather) ----
    gather64_bn<<<vec_grid, 256, 0, stream>>>(A, ss0, rowptr, cnt, elist, C);
    mlp_kernel<64><<<row_grid, 256, 0, stream>>>(C, W1[1], B1[1], W2[1], B2[1], A);
    bn_stats<<<row_grid, 256, 0, stream>>>(A, acc + 128);
    bn_finalize<<<1, 64, 0, stream>>>(acc + 128, GM[1], BT[1], ss1);

    // ---- layer 2 ----
    gather64_bn<<<vec_grid, 256, 0, stream>>>(A, ss1, rowptr, cnt, elist, C);
    mlp_kernel<64><<<row_grid, 256, 0, stream>>>(C, W1[2], B1[2], W2[2], B2[2], A);
    bn_stats<<<row_grid, 256, 0, stream>>>(A, acc + 256);
    bn_finalize<<<1, 64, 0, stream>>>(acc + 256, GM[2], BT[2], ss2);

    // ---- pool (BN+relu fused, deterministic per-graph reduction) ----
    pool_bn<<<N_GRAPHS, 256, 0, stream>>>(A, ss2, grow, pooled);

    // ---- readout ----
    final_proj<<<N_GRAPHS / 4, 256, 0, stream>>>(pooled, PW, PB, out);
}

// Round 12
// 550.861 us; speedup vs baseline: 1.3767x; 1.0145x over previous
//
#include <hip/hip_runtime.h>

#define N_NODES 100000
#define N_EDGES 1600000
#define N_GRAPHS 1024
#define BN_EPS 1e-5f
#define BSH 6
#define BNODES 64            // nodes per bucket = 1<<BSH
#define NBUCK 1563           // ceil(100000/64)
#define NB 256               // multi-split blocks (chunks) -- was 128, raised for occupancy
#define CH 6250              // edges per chunk = N_EDGES/NB
#define MS_N (NBUCK * NB)    // 400128 scan elements
#define MS_SBLK ((MS_N + 1023) / 1024)  // 391

// ================= deterministic multi-split CSR build (dst -> list of src) =================
// Pass A: per-chunk LDS histogram over 1563 buckets -> hist[bucket][block]
__global__ __launch_bounds__(256) void msplit_hist(const int* __restrict__ dst,
                                                   int* __restrict__ hist_g) {
    __shared__ int lh[NBUCK];
    for (int i = threadIdx.x; i < NBUCK; i += 256) lh[i] = 0;
    __syncthreads();
    int e0 = blockIdx.x * CH;
    int e1 = min(e0 + CH, N_EDGES);
    for (int e = e0 + threadIdx.x; e < e1; e += 256)
        atomicAdd(&lh[dst[e] >> BSH], 1);
    __syncthreads();
    for (int i = threadIdx.x; i < NBUCK; i += 256)
        hist_g[i * NB + blockIdx.x] = lh[i];
}

// Scan chain over MS_N entries (bucket-major) -> exact (bucket,block) bases
__global__ __launch_bounds__(256) void ms_scan_blocks(const int* __restrict__ in,
                                                      int* __restrict__ out,
                                                      int* __restrict__ bsum) {
    __shared__ int ts[256];
    int base = blockIdx.x * 1024 + threadIdx.x * 4;
    int c[4];
#pragma unroll
    for (int i = 0; i < 4; i++) {
        int idx = base + i;
        c[i] = (idx < MS_N) ? in[idx] : 0;
    }
    int s = c[0] + c[1] + c[2] + c[3];
    ts[threadIdx.x] = s;
    __syncthreads();
    for (int off = 1; off < 256; off <<= 1) {
        int v = (threadIdx.x >= off) ? ts[threadIdx.x - off] : 0;
        __syncthreads();
        ts[threadIdx.x] += v;
        __syncthreads();
    }
    int run = ts[threadIdx.x] - s;  // exclusive
#pragma unroll
    for (int i = 0; i < 4; i++) {
        int idx = base + i;
        if (idx < MS_N) out[idx] = run;
        run += c[i];
    }
    if (threadIdx.x == 255) bsum[blockIdx.x] = ts[255];
}

__global__ void ms_scan_sums(int* bsum) {
    if (threadIdx.x == 0) {
        int run = 0;
        for (int i = 0; i < MS_SBLK; i++) {
            int v = bsum[i];
            bsum[i] = run;
            run += v;
        }
    }
}

__global__ __launch_bounds__(256) void ms_scan_apply(int* __restrict__ data,
                                                     const int* __restrict__ bsum,
                                                     int* __restrict__ bptr) {
    int i = blockIdx.x * 256 + threadIdx.x;
    if (i < MS_N) {
        int v = data[i] + bsum[i >> 10];
        data[i] = v;
        if ((i & (NB - 1)) == 0) bptr[i / NB] = v;  // bucket base
    }
    if (i == 0) bptr[NBUCK] = N_EDGES;
}

// Pass B: place edges at base + LDS-rank. No global atomics.
// Packed payload: (dst&63)<<17 | src   (src < 2^17)
__global__ __launch_bounds__(256) void msplit_place(const int* __restrict__ src,
                                                    const int* __restrict__ dst,
                                                    const int* __restrict__ hist_s,
                                                    int* __restrict__ ebuf) {
    __shared__ int lbase[NBUCK];
    for (int i = threadIdx.x; i < NBUCK; i += 256)
        lbase[i] = hist_s[i * NB + blockIdx.x];
    __syncthreads();
    int e0 = blockIdx.x * CH;
    int e1 = min(e0 + CH, N_EDGES);
    for (int e = e0 + threadIdx.x; e < e1; e += 256) {
        int d = dst[e];
        int p = atomicAdd(&lbase[d >> BSH], 1);  // LDS atomic: unique rank
        ebuf[p] = ((d & (BNODES - 1)) << 17) | src[e];
    }
}

// Stage 4: one block per bucket. LDS count -> LDS scan -> rowptr/cnt -> local scatter.
__global__ __launch_bounds__(256) void bucket_csr(const int* __restrict__ ebuf,
                                                  const int* __restrict__ bptr,
                                                  int* __restrict__ rowptr,
                                                  int* __restrict__ cnt,
                                                  int* __restrict__ elist) {
    int b = blockIdx.x;
    int rs = bptr[b], re = bptr[b + 1];
    int nbase = b << BSH;
    __shared__ int lcnt[BNODES], loff[BNODES];
    if (threadIdx.x < BNODES) lcnt[threadIdx.x] = 0;
    __syncthreads();
    for (int i = rs + threadIdx.x; i < re; i += 256)
        atomicAdd(&lcnt[ebuf[i] >> 17], 1);
    __syncthreads();
    if (threadIdx.x < BNODES) loff[threadIdx.x] = lcnt[threadIdx.x];
    __syncthreads();
    for (int off = 1; off < BNODES; off <<= 1) {
        int v = 0;
        if (threadIdx.x < BNODES && threadIdx.x >= off) v = loff[threadIdx.x - off];
        __syncthreads();
        if (threadIdx.x < BNODES) loff[threadIdx.x] += v;
        __syncthreads();
    }
    if (threadIdx.x < BNODES) {
        loff[threadIdx.x] -= lcnt[threadIdx.x];  // exclusive
        int n = nbase + threadIdx.x;
        if (n < N_NODES) {
            rowptr[n] = rs + loff[threadIdx.x];
            cnt[n] = lcnt[threadIdx.x];
        }
    }
    __syncthreads();
    for (int i = rs + threadIdx.x; i < re; i += 256) {
        int pk = ebuf[i];
        int p = atomicAdd(&loff[pk >> 17], 1);
        elist[rs + p] = pk & 0x1FFFF;
    }
}

// ================= graph boundaries via binary search (batch is sorted) =================
__global__ __launch_bounds__(256) void gbounds(const int* __restrict__ batch,
                                               int* __restrict__ grow) {
    int g = blockIdx.x * 256 + threadIdx.x;
    if (g > N_GRAPHS) return;
    int lo = 0, hi = N_NODES;
    while (lo < hi) {
        int mid = (lo + hi) >> 1;
        if (batch[mid] < g) lo = mid + 1;
        else hi = mid;
    }
    grow[g] = lo;
}

// ================= pad x (100K x 7) -> x8 (100K x 8, L2-resident, 32B rows) =================
__global__ __launch_bounds__(256) void pad8(const float* __restrict__ x,
                                            float* __restrict__ x8) {
    int t = blockIdx.x * 256 + threadIdx.x;
    if (t >= N_NODES * 8) return;
    int n = t >> 3, f = t & 7;
    x8[t] = (f < 7) ? x[(size_t)n * 7 + f] : 0.0f;
}

// ================= aggregation by gather (no fp32 atomics) =================
// 8 lanes per node, one feature each; x8 rows are 32B-aligned & coalesced
__global__ __launch_bounds__(256) void gather7(const float* __restrict__ x8,
                                               const int* __restrict__ rowptr,
                                               const int* __restrict__ cnt,
                                               const int* __restrict__ elist,
                                               float* __restrict__ agg) {
    int t = blockIdx.x * 256 + threadIdx.x;
    int n = t >> 3, f = t & 7;
    if (n >= N_NODES) return;
    int start = rowptr[n], k = cnt[n];
    float a = x8[(size_t)n * 8 + f];
    for (int i = 0; i < k; i++) {
        int s = elist[start + i];
        a += x8[(size_t)s * 8 + f];   // f==7 lanes add 0 (pad), keep full 32B coalescing
    }
    if (f < 7) agg[(size_t)n * 7 + f] = a;
}

// ONE WAVE PER NODE: 16 float4-columns x 4 edge-quarters -> 4 independent
// load chains per wave, then shfl_xor(16/32) cross-quarter reduction.
// BN(scale/shift)+relu applied per gathered row; self term added by quarter 0.
__global__ __launch_bounds__(256) void gather64_bn(const float* __restrict__ h2,
                                                   const float* __restrict__ ss,
                                                   const int* __restrict__ rowptr,
                                                   const int* __restrict__ cnt,
                                                   const int* __restrict__ elist,
                                                   float* __restrict__ agg) {
    int t = blockIdx.x * 256 + threadIdx.x;
    int n = t >> 6;                 // one 64-lane wave per node
    if (n >= N_NODES) return;
    int l = t & 63;
    int c = l & 15, q = l >> 4;     // column, edge-quarter
    float4 sc = ((const float4*)ss)[c];
    float4 sh = ((const float4*)(ss + 64))[c];
    int start = rowptr[n], k = cnt[n];
    const float4* h4 = (const float4*)h2;
    float4 a = {0.f, 0.f, 0.f, 0.f};
    for (int i = q; i < k; i += 4) {
        int s = elist[start + i];   // 16 lanes of a quarter: broadcast read
        float4 w = h4[(size_t)s * 16 + c];  // coalesced 256B row
        a.x += fmaxf(fmaf(w.x, sc.x, sh.x), 0.0f);
        a.y += fmaxf(fmaf(w.y, sc.y, sh.y), 0.0f);
        a.z += fmaxf(fmaf(w.z, sc.z, sh.z), 0.0f);
        a.w += fmaxf(fmaf(w.w, sc.w, sh.w), 0.0f);
    }
    // reduce across the 4 quarters (lanes c, c+16, c+32, c+48)
    a.x += __shfl_xor(a.x, 16); a.y += __shfl_xor(a.y, 16);
    a.z += __shfl_xor(a.z, 16); a.w += __shfl_xor(a.w, 16);
    a.x += __shfl_xor(a.x, 32); a.y += __shfl_xor(a.y, 32);
    a.z += __shfl_xor(a.z, 32); a.w += __shfl_xor(a.w, 32);
    if (q == 0) {
        float4 v = h4[(size_t)n * 16 + c];  // self term
        a.x += fmaxf(fmaf(v.x, sc.x, sh.x), 0.0f);
        a.y += fmaxf(fmaf(v.y, sc.y, sh.y), 0.0f);
        a.z += fmaxf(fmaf(v.z, sc.z, sh.z), 0.0f);
        a.w += fmaxf(fmaf(v.w, sc.w, sh.w), 0.0f);
        ((float4*)agg)[(size_t)n * 16 + c] = a;
    }
}

// ================= MLP: h2 = relu(agg@w1+b1)@w2+b2 =================
template <int DIN>
__global__ __launch_bounds__(256) void mlp_kernel(const float* __restrict__ agg,
                                                  const float* __restrict__ w1,
                                                  const float* __restrict__ b1,
                                                  const float* __restrict__ w2,
                                                  const float* __restrict__ b2,
                                                  float* __restrict__ h2out) {
    int row = blockIdx.x * 256 + threadIdx.x;
    if (row >= N_NODES) return;
    const float* xr = agg + (size_t)row * DIN;

    float h1[64];
#pragma unroll
    for (int j = 0; j < 64; j++) h1[j] = b1[j];

    if constexpr (DIN == 7) {
#pragma unroll
        for (int k = 0; k < 7; k++) {
            float xv = xr[k];
#pragma unroll
            for (int j = 0; j < 64; j++) h1[j] = fmaf(xv, w1[k * 64 + j], h1[j]);
        }
    } else {
        const float4* xp = (const float4*)xr;
        for (int kk = 0; kk < DIN / 4; kk++) {
            float4 xv = xp[kk];
            const float* w = w1 + kk * 4 * 64;
#pragma unroll
            for (int j = 0; j < 64; j++) h1[j] = fmaf(xv.x, w[j], h1[j]);
#pragma unroll
            for (int j = 0; j < 64; j++) h1[j] = fmaf(xv.y, w[64 + j], h1[j]);
#pragma unroll
            for (int j = 0; j < 64; j++) h1[j] = fmaf(xv.z, w[128 + j], h1[j]);
#pragma unroll
            for (int j = 0; j < 64; j++) h1[j] = fmaf(xv.w, w[192 + j], h1[j]);
        }
    }
#pragma unroll
    for (int j = 0; j < 64; j++) h1[j] = fmaxf(h1[j], 0.0f);

    for (int j4 = 0; j4 < 16; j4++) {
        float4 o;
        float* ov = (float*)&o;
#pragma unroll
        for (int jj = 0; jj < 4; jj++) {
            int j = j4 * 4 + jj;
            float a = b2[j];
#pragma unroll
            for (int k = 0; k < 64; k++) a = fmaf(h1[k], w2[k * 64 + j], a);
            ov[jj] = a;
        }
        ((float4*)(h2out + (size_t)row * 64))[j4] = o;
    }
}

// ================= BN stats: per-feature sum / sumsq (fp64 accumulators) =================
__global__ __launch_bounds__(256) void bn_stats(const float* __restrict__ h2,
                                                double* __restrict__ acc) {
    long base = (long)blockIdx.x * 256 * 64;
    long end = base + 256L * 64;
    long lim = (long)N_NODES * 64;
    if (end > lim) end = lim;
    float s = 0.f, sq = 0.f;
    for (long i = base + threadIdx.x; i < end; i += 256) {
        float v = h2[i];
        s += v;
        sq += v * v;
    }
    __shared__ float ls[256], lq[256];
    ls[threadIdx.x] = s;
    lq[threadIdx.x] = sq;
    __syncthreads();
    if (threadIdx.x < 64) {
        float S = ls[threadIdx.x] + ls[threadIdx.x + 64] + ls[threadIdx.x + 128] + ls[threadIdx.x + 192];
        float Q = lq[threadIdx.x] + lq[threadIdx.x + 64] + lq[threadIdx.x + 128] + lq[threadIdx.x + 192];
        atomicAdd(&acc[threadIdx.x], (double)S);
        atomicAdd(&acc[64 + threadIdx.x], (double)Q);
    }
}

__global__ void bn_finalize(const double* __restrict__ acc, const float* __restrict__ gamma,
                            const float* __restrict__ beta, float* __restrict__ ss) {
    int j = threadIdx.x;
    if (j >= 64) return;
    double inv = 1.0 / (double)N_NODES;
    double mean = acc[j] * inv;
    double var = acc[64 + j] * inv - mean * mean;
    float scale = gamma[j] / sqrtf((float)var + BN_EPS);
    ss[j] = scale;
    ss[64 + j] = beta[j] - (float)mean * scale;
}

// ================= pool: BN+relu+mean over each graph's nodes (no atomics) =================
__global__ __launch_bounds__(256) void pool_bn(const float* __restrict__ h2,
                                               const float* __restrict__ ss,
                                               const int* __restrict__ grow,
                                               float* __restrict__ pooled) {
    int g = blockIdx.x;
    int start = grow[g], end = grow[g + 1];
    int c = threadIdx.x & 15, grp = threadIdx.x >> 4;
    float4 sc = ((const float4*)ss)[c];
    float4 sh = ((const float4*)(ss + 64))[c];
    const float4* h4 = (const float4*)h2;
    float4 a = {0.f, 0.f, 0.f, 0.f};
    for (int n = start + grp; n < end; n += 16) {
        float4 v = h4[(size_t)n * 16 + c];
        a.x += fmaxf(fmaf(v.x, sc.x, sh.x), 0.0f);
        a.y += fmaxf(fmaf(v.y, sc.y, sh.y), 0.0f);
        a.z += fmaxf(fmaf(v.z, sc.z, sh.z), 0.0f);
        a.w += fmaxf(fmaf(v.w, sc.w, sh.w), 0.0f);
    }
    __shared__ float4 ls[256];
    ls[threadIdx.x] = a;
    __syncthreads();
    for (int off = 128; off >= 16; off >>= 1) {
        if (threadIdx.x < off) {
            float4 b = ls[threadIdx.x + off];
            ls[threadIdx.x].x += b.x;
            ls[threadIdx.x].y += b.y;
            ls[threadIdx.x].z += b.z;
            ls[threadIdx.x].w += b.w;
        }
        __syncthreads();
    }
    if (threadIdx.x < 16) {
        float inv = 1.0f / fmaxf((float)(end - start), 1.0f);
        float4 r = ls[threadIdx.x];
        r.x *= inv; r.y *= inv; r.z *= inv; r.w *= inv;
        ((float4*)pooled)[(size_t)g * 16 + threadIdx.x] = r;
    }
}

// ================= final: proj + L2 normalize; one wave per graph =================
__global__ __launch_bounds__(256) void final_proj(const float* __restrict__ pooled,
                                                  const float* __restrict__ pw,
                                                  const float* __restrict__ pb,
                                                  float* __restrict__ out) {
    __shared__ float sw[64 * 64];
    for (int i = threadIdx.x; i < 4096; i += 256) sw[i] = pw[i];
    __syncthreads();
    int g = blockIdx.x * 4 + (threadIdx.x >> 6);
    int j = threadIdx.x & 63;
    if (g >= N_GRAPHS) return;
    float a = pb[j];
#pragma unroll
    for (int k = 0; k < 64; k++) a = fmaf(pooled[(size_t)g * 64 + k], sw[k * 64 + j], a);
    float ss2 = a * a;
#pragma unroll
    for (int off = 1; off < 64; off <<= 1) ss2 += __shfl_xor(ss2, off);
    out[(size_t)g * 64 + j] = a / fmaxf(sqrtf(ss2), 1e-12f);
}

extern "C" void kernel_launch(void* const* d_in, const int* in_sizes, int n_in,
                              void* d_out, int out_size, void* d_ws, size_t ws_size,
                              hipStream_t stream) {
    const float* x = (const float*)d_in[0];
    const int* eidx = (const int*)d_in[1];
    const int* batch = (const int*)d_in[2];
    const int* src = eidx;
    const int* dst = eidx + N_EDGES;
    const float* W1[3] = {(const float*)d_in[3], (const float*)d_in[9], (const float*)d_in[15]};
    const float* B1[3] = {(const float*)d_in[4], (const float*)d_in[10], (const float*)d_in[16]};
    const float* W2[3] = {(const float*)d_in[5], (const float*)d_in[11], (const float*)d_in[17]};
    const float* B2[3] = {(const float*)d_in[6], (const float*)d_in[12], (const float*)d_in[18]};
    const float* GM[3] = {(const float*)d_in[7], (const float*)d_in[13], (const float*)d_in[19]};
    const float* BT[3] = {(const float*)d_in[8], (const float*)d_in[14], (const float*)d_in[20]};
    const float* PW = (const float*)d_in[21];
    const float* PB = (const float*)d_in[22];
    float* out = (float*)d_out;

    char* ws = (char*)d_ws;
    size_t off = 0;
    auto alloc = [&](size_t bytes) -> void* {
        void* p = ws + off;
        off += (bytes + 255) & ~(size_t)255;
        return p;
    };
    float* A    = (float*)alloc((size_t)N_NODES * 64 * 4);  // h2 buffer
    float* C    = (float*)alloc((size_t)N_NODES * 64 * 4);  // agg buffer
    float* agg0 = (float*)alloc((size_t)N_NODES * 7 * 4);
    float* x8   = (float*)alloc((size_t)N_NODES * 8 * 4);
    int* cnt    = (int*)alloc((size_t)N_NODES * 4);
    int* rowptr = (int*)alloc((size_t)N_NODES * 4);
    int* elist  = (int*)alloc((size_t)N_EDGES * 4);
    int* ebuf   = (int*)alloc((size_t)N_EDGES * 4);   // packed (dlo<<17)|src
    int* hist_g = (int*)alloc((size_t)MS_N * 4);
    int* hist_s = (int*)alloc((size_t)MS_N * 4);
    int* msum   = (int*)alloc((size_t)MS_SBLK * 4);
    int* bptr   = (int*)alloc((size_t)(NBUCK + 1) * 4);
    int* grow   = (int*)alloc(1025 * 4);
    double* acc = (double*)alloc(3 * 128 * sizeof(double));
    float* ss0    = (float*)alloc(128 * 4);
    float* ss1    = (float*)alloc(128 * 4);
    float* ss2    = (float*)alloc(128 * 4);
    float* pooled = (float*)alloc((size_t)N_GRAPHS * 64 * 4);

    hipMemsetAsync(acc, 0, 3 * 128 * sizeof(double), stream);

    const int row_grid = (N_NODES + 255) / 256;        // 391
    const int g7_grid = (N_NODES * 8 + 255) / 256;     // 3125
    const int g64_grid = (N_NODES * 64 + 255) / 256;   // 25000 (wave per node)

    // ---- deterministic multi-split CSR build (reused by all 3 layers) ----
    msplit_hist<<<NB, 256, 0, stream>>>(dst, hist_g);
    ms_scan_blocks<<<MS_SBLK, 256, 0, stream>>>(hist_g, hist_s, msum);
    ms_scan_sums<<<1, 64, 0, stream>>>(msum);
    ms_scan_apply<<<(MS_N + 255) / 256, 256, 0, stream>>>(hist_s, msum, bptr);
    msplit_place<<<NB, 256, 0, stream>>>(src, dst, hist_s, ebuf);
    bucket_csr<<<NBUCK, 256, 0, stream>>>(ebuf, bptr, rowptr, cnt, elist);
    gbounds<<<5, 256, 0, stream>>>(batch, grow);
    pad8<<<g7_grid, 256, 0, stream>>>(x, x8);

    // ---- layer 0 ----
    gather7<<<g7_grid, 256, 0, stream>>>(x8, rowptr, cnt, elist, agg0);
    mlp_kernel<7><<<row_grid, 256, 0, stream>>>(agg0, W1[0], B1[0], W2[0], B2[0], A);
    bn_stats<<<row_grid, 256, 0, stream>>>(A, acc);
    bn_finalize<<<1, 64, 0, stream>>>(acc, GM[0], BT[0], ss0);

    // ---- layer 1 (BN+relu of layer 0 fused into gather) ----
    gather64_bn<<<g64_grid, 256, 0, stream>>>(A, ss0, rowptr, cnt, elist, C);
    mlp_kernel<64><<<row_grid, 256, 0, stream>>>(C, W1[1], B1[1], W2[1], B2[1], A);
    bn_stats<<<row_grid, 256, 0, stream>>>(A, acc + 128);
    bn_finalize<<<1, 64, 0, stream>>>(acc + 128, GM[1], BT[1], ss1);

    // ---- layer 2 ----
    gather64_bn<<<g64_grid, 256, 0, stream>>>(A, ss1, rowptr, cnt, elist, C);
    mlp_kernel<64><<<row_grid, 256, 0, stream>>>(C, W1[2], B1[2], W2[2], B2[2], A);
    bn_stats<<<row_grid, 256, 0, stream>>>(A, acc + 256);
    bn_finalize<<<1, 64, 0, stream>>>(acc + 256, GM[2], BT[2], ss2);

    // ---- pool (BN+relu fused, deterministic per-graph reduction) ----
    pool_bn<<<N_GRAPHS, 256, 0, stream>>>(A, ss2, grow, pooled);

    // ---- readout ----
    final_proj<<<N_GRAPHS / 4, 256, 0, stream>>>(pooled, PW, PB, out);
}

// Round 14
// 536.664 us; speedup vs baseline: 1.4131x; 1.0265x over previous
//
#include <hip/hip_runtime.h>
#include <hip/hip_fp16.h>

#define N_NODES 100000
#define N_EDGES 1600000
#define N_GRAPHS 1024
#define BN_EPS 1e-5f
#define BSH 6
#define BNODES 64            // nodes per bucket = 1<<BSH
#define NBUCK 1563           // ceil(100000/64)
#define NB 256               // multi-split blocks (chunks)
#define CH 6250              // edges per chunk = N_EDGES/NB
#define MS_N (NBUCK * NB)    // 400128 scan elements
#define MS_SBLK ((MS_N + 1023) / 1024)  // 391

// ================= deterministic multi-split CSR build (dst -> list of src) =================
__global__ __launch_bounds__(256) void msplit_hist(const int* __restrict__ dst,
                                                   int* __restrict__ hist_g) {
    __shared__ int lh[NBUCK];
    for (int i = threadIdx.x; i < NBUCK; i += 256) lh[i] = 0;
    __syncthreads();
    int e0 = blockIdx.x * CH;
    int e1 = min(e0 + CH, N_EDGES);
    for (int e = e0 + threadIdx.x; e < e1; e += 256)
        atomicAdd(&lh[dst[e] >> BSH], 1);
    __syncthreads();
    for (int i = threadIdx.x; i < NBUCK; i += 256)
        hist_g[i * NB + blockIdx.x] = lh[i];
}

__global__ __launch_bounds__(256) void ms_scan_blocks(const int* __restrict__ in,
                                                      int* __restrict__ out,
                                                      int* __restrict__ bsum) {
    __shared__ int ts[256];
    int base = blockIdx.x * 1024 + threadIdx.x * 4;
    int c[4];
#pragma unroll
    for (int i = 0; i < 4; i++) {
        int idx = base + i;
        c[i] = (idx < MS_N) ? in[idx] : 0;
    }
    int s = c[0] + c[1] + c[2] + c[3];
    ts[threadIdx.x] = s;
    __syncthreads();
    for (int off = 1; off < 256; off <<= 1) {
        int v = (threadIdx.x >= off) ? ts[threadIdx.x - off] : 0;
        __syncthreads();
        ts[threadIdx.x] += v;
        __syncthreads();
    }
    int run = ts[threadIdx.x] - s;  // exclusive
#pragma unroll
    for (int i = 0; i < 4; i++) {
        int idx = base + i;
        if (idx < MS_N) out[idx] = run;
        run += c[i];
    }
    if (threadIdx.x == 255) bsum[blockIdx.x] = ts[255];
}

__global__ void ms_scan_sums(int* bsum) {
    if (threadIdx.x == 0) {
        int run = 0;
        for (int i = 0; i < MS_SBLK; i++) {
            int v = bsum[i];
            bsum[i] = run;
            run += v;
        }
    }
}

__global__ __launch_bounds__(256) void ms_scan_apply(int* __restrict__ data,
                                                     const int* __restrict__ bsum,
                                                     int* __restrict__ bptr) {
    int i = blockIdx.x * 256 + threadIdx.x;
    if (i < MS_N) {
        int v = data[i] + bsum[i >> 10];
        data[i] = v;
        if ((i & (NB - 1)) == 0) bptr[i / NB] = v;  // bucket base
    }
    if (i == 0) bptr[NBUCK] = N_EDGES;
}

// Packed payload: (dst&63)<<17 | src   (src < 2^17)
__global__ __launch_bounds__(256) void msplit_place(const int* __restrict__ src,
                                                    const int* __restrict__ dst,
                                                    const int* __restrict__ hist_s,
                                                    int* __restrict__ ebuf) {
    __shared__ int lbase[NBUCK];
    for (int i = threadIdx.x; i < NBUCK; i += 256)
        lbase[i] = hist_s[i * NB + blockIdx.x];
    __syncthreads();
    int e0 = blockIdx.x * CH;
    int e1 = min(e0 + CH, N_EDGES);
    for (int e = e0 + threadIdx.x; e < e1; e += 256) {
        int d = dst[e];
        int p = atomicAdd(&lbase[d >> BSH], 1);  // LDS atomic: unique rank
        ebuf[p] = ((d & (BNODES - 1)) << 17) | src[e];
    }
}

__global__ __launch_bounds__(256) void bucket_csr(const int* __restrict__ ebuf,
                                                  const int* __restrict__ bptr,
                                                  int* __restrict__ rowptr,
                                                  int* __restrict__ cnt,
                                                  int* __restrict__ elist) {
    int b = blockIdx.x;
    int rs = bptr[b], re = bptr[b + 1];
    int nbase = b << BSH;
    __shared__ int lcnt[BNODES], loff[BNODES];
    if (threadIdx.x < BNODES) lcnt[threadIdx.x] = 0;
    __syncthreads();
    for (int i = rs + threadIdx.x; i < re; i += 256)
        atomicAdd(&lcnt[ebuf[i] >> 17], 1);
    __syncthreads();
    if (threadIdx.x < BNODES) loff[threadIdx.x] = lcnt[threadIdx.x];
    __syncthreads();
    for (int off = 1; off < BNODES; off <<= 1) {
        int v = 0;
        if (threadIdx.x < BNODES && threadIdx.x >= off) v = loff[threadIdx.x - off];
        __syncthreads();
        if (threadIdx.x < BNODES) loff[threadIdx.x] += v;
        __syncthreads();
    }
    if (threadIdx.x < BNODES) {
        loff[threadIdx.x] -= lcnt[threadIdx.x];  // exclusive
        int n = nbase + threadIdx.x;
        if (n < N_NODES) {
            rowptr[n] = rs + loff[threadIdx.x];
            cnt[n] = lcnt[threadIdx.x];
        }
    }
    __syncthreads();
    for (int i = rs + threadIdx.x; i < re; i += 256) {
        int pk = ebuf[i];
        int p = atomicAdd(&loff[pk >> 17], 1);
        elist[rs + p] = pk & 0x1FFFF;
    }
}

// ================= graph boundaries via binary search (batch is sorted) =================
__global__ __launch_bounds__(256) void gbounds(const int* __restrict__ batch,
                                               int* __restrict__ grow) {
    int g = blockIdx.x * 256 + threadIdx.x;
    if (g > N_GRAPHS) return;
    int lo = 0, hi = N_NODES;
    while (lo < hi) {
        int mid = (lo + hi) >> 1;
        if (batch[mid] < g) lo = mid + 1;
        else hi = mid;
    }
    grow[g] = lo;
}

// ================= pad x (100K x 7) -> x8 (100K x 8, 32B rows) =================
__global__ __launch_bounds__(256) void pad8(const float* __restrict__ x,
                                            float* __restrict__ x8) {
    int t = blockIdx.x * 256 + threadIdx.x;
    if (t >= N_NODES * 8) return;
    int n = t >> 3, f = t & 7;
    x8[t] = (f < 7) ? x[(size_t)n * 7 + f] : 0.0f;
}

// ================= aggregation by gather (no fp32 atomics) =================
__global__ __launch_bounds__(256) void gather7(const float* __restrict__ x8,
                                               const int* __restrict__ rowptr,
                                               const int* __restrict__ cnt,
                                               const int* __restrict__ elist,
                                               float* __restrict__ agg) {
    int t = blockIdx.x * 256 + threadIdx.x;
    int n = t >> 3, f = t & 7;
    if (n >= N_NODES) return;
    int start = rowptr[n], k = cnt[n];
    float a = x8[(size_t)n * 8 + f];
    for (int i = 0; i < k; i++) {
        int s = elist[start + i];
        a += x8[(size_t)s * 8 + f];
    }
    if (f < 7) agg[(size_t)n * 7 + f] = a;
}

// fp16 gather: 16 lanes/node, 8B (4 halves) per lane -> 128B coalesced row.
// BN(scale/shift)+relu in fp32 on the fly; fp32 accumulate; includes self term.
__global__ __launch_bounds__(256) void gather64_bn(const __half* __restrict__ h16,
                                                   const float* __restrict__ ss,
                                                   const int* __restrict__ rowptr,
                                                   const int* __restrict__ cnt,
                                                   const int* __restrict__ elist,
                                                   float* __restrict__ agg) {
    int t = blockIdx.x * 256 + threadIdx.x;
    int n = t >> 4, c = t & 15;
    if (n >= N_NODES) return;
    float4 sc = ((const float4*)ss)[c];
    float4 sh = ((const float4*)(ss + 64))[c];
    int start = rowptr[n], k = cnt[n];
    float4 a = {0.f, 0.f, 0.f, 0.f};
    for (int i = 0; i < k; i++) {
        int s = elist[start + i];
        float2 raw = ((const float2*)(h16 + (size_t)s * 64))[c];
        float2 f0 = __half22float2(*(const __half2*)&raw.x);
        float2 f1 = __half22float2(*(const __half2*)&raw.y);
        a.x += fmaxf(fmaf(f0.x, sc.x, sh.x), 0.0f);
        a.y += fmaxf(fmaf(f0.y, sc.y, sh.y), 0.0f);
        a.z += fmaxf(fmaf(f1.x, sc.z, sh.z), 0.0f);
        a.w += fmaxf(fmaf(f1.y, sc.w, sh.w), 0.0f);
    }
    {   // self term
        float2 raw = ((const float2*)(h16 + (size_t)n * 64))[c];
        float2 f0 = __half22float2(*(const __half2*)&raw.x);
        float2 f1 = __half22float2(*(const __half2*)&raw.y);
        a.x += fmaxf(fmaf(f0.x, sc.x, sh.x), 0.0f);
        a.y += fmaxf(fmaf(f0.y, sc.y, sh.y), 0.0f);
        a.z += fmaxf(fmaf(f1.x, sc.z, sh.z), 0.0f);
        a.w += fmaxf(fmaf(f1.y, sc.w, sh.w), 0.0f);
    }
    ((float4*)agg)[(size_t)n * 16 + c] = a;
}

// ================= MLP: h2 = relu(agg@w1+b1)@w2+b2 =================
template <int DIN>
__global__ __launch_bounds__(256) void mlp_kernel(const float* __restrict__ agg,
                                                  const float* __restrict__ w1,
                                                  const float* __restrict__ b1,
                                                  const float* __restrict__ w2,
                                                  const float* __restrict__ b2,
                                                  float* __restrict__ h2out) {
    int row = blockIdx.x * 256 + threadIdx.x;
    if (row >= N_NODES) return;
    const float* xr = agg + (size_t)row * DIN;

    float h1[64];
#pragma unroll
    for (int j = 0; j < 64; j++) h1[j] = b1[j];

    if constexpr (DIN == 7) {
#pragma unroll
        for (int k = 0; k < 7; k++) {
            float xv = xr[k];
#pragma unroll
            for (int j = 0; j < 64; j++) h1[j] = fmaf(xv, w1[k * 64 + j], h1[j]);
        }
    } else {
        const float4* xp = (const float4*)xr;
        for (int kk = 0; kk < DIN / 4; kk++) {
            float4 xv = xp[kk];
            const float* w = w1 + kk * 4 * 64;
#pragma unroll
            for (int j = 0; j < 64; j++) h1[j] = fmaf(xv.x, w[j], h1[j]);
#pragma unroll
            for (int j = 0; j < 64; j++) h1[j] = fmaf(xv.y, w[64 + j], h1[j]);
#pragma unroll
            for (int j = 0; j < 64; j++) h1[j] = fmaf(xv.z, w[128 + j], h1[j]);
#pragma unroll
            for (int j = 0; j < 64; j++) h1[j] = fmaf(xv.w, w[192 + j], h1[j]);
        }
    }
#pragma unroll
    for (int j = 0; j < 64; j++) h1[j] = fmaxf(h1[j], 0.0f);

    for (int j4 = 0; j4 < 16; j4++) {
        float4 o;
        float* ov = (float*)&o;
#pragma unroll
        for (int jj = 0; jj < 4; jj++) {
            int j = j4 * 4 + jj;
            float a = b2[j];
#pragma unroll
            for (int k = 0; k < 64; k++) a = fmaf(h1[k], w2[k * 64 + j], a);
            ov[jj] = a;
        }
        ((float4*)(h2out + (size_t)row * 64))[j4] = o;
    }
}

// ================= BN stats + fp16 mirror of h2 =================
__global__ __launch_bounds__(256) void bn_stats(const float* __restrict__ h2,
                                                double* __restrict__ acc,
                                                __half* __restrict__ h16) {
    long base = (long)blockIdx.x * 256 * 64;
    long end = base + 256L * 64;
    long lim = (long)N_NODES * 64;
    if (end > lim) end = lim;
    float s = 0.f, sq = 0.f;
    for (long i = base + threadIdx.x; i < end; i += 256) {
        float v = h2[i];
        s += v;
        sq += v * v;
        h16[i] = __float2half(v);
    }
    __shared__ float ls[256], lq[256];
    ls[threadIdx.x] = s;
    lq[threadIdx.x] = sq;
    __syncthreads();
    if (threadIdx.x < 64) {
        float S = ls[threadIdx.x] + ls[threadIdx.x + 64] + ls[threadIdx.x + 128] + ls[threadIdx.x + 192];
        float Q = lq[threadIdx.x] + lq[threadIdx.x + 64] + lq[threadIdx.x + 128] + lq[threadIdx.x + 192];
        atomicAdd(&acc[threadIdx.x], (double)S);
        atomicAdd(&acc[64 + threadIdx.x], (double)Q);
    }
}

__global__ void bn_finalize(const double* __restrict__ acc, const float* __restrict__ gamma,
                            const float* __restrict__ beta, float* __restrict__ ss) {
    int j = threadIdx.x;
    if (j >= 64) return;
    double inv = 1.0 / (double)N_NODES;
    double mean = acc[j] * inv;
    double var = acc[64 + j] * inv - mean * mean;
    float scale = gamma[j] / sqrtf((float)var + BN_EPS);
    ss[j] = scale;
    ss[64 + j] = beta[j] - (float)mean * scale;
}

// ================= pool: BN+relu+mean over each graph's nodes (fp16 input) =================
__global__ __launch_bounds__(256) void pool_bn(const __half* __restrict__ h16,
                                               const float* __restrict__ ss,
                                               const int* __restrict__ grow,
                                               float* __restrict__ pooled) {
    int g = blockIdx.x;
    int start = grow[g], end = grow[g + 1];
    int c = threadIdx.x & 15, grp = threadIdx.x >> 4;
    float4 sc = ((const float4*)ss)[c];
    float4 sh = ((const float4*)(ss + 64))[c];
    float4 a = {0.f, 0.f, 0.f, 0.f};
    for (int n = start + grp; n < end; n += 16) {
        float2 raw = ((const float2*)(h16 + (size_t)n * 64))[c];
        float2 f0 = __half22float2(*(const __half2*)&raw.x);
        float2 f1 = __half22float2(*(const __half2*)&raw.y);
        a.x += fmaxf(fmaf(f0.x, sc.x, sh.x), 0.0f);
        a.y += fmaxf(fmaf(f0.y, sc.y, sh.y), 0.0f);
        a.z += fmaxf(fmaf(f1.x, sc.z, sh.z), 0.0f);
        a.w += fmaxf(fmaf(f1.y, sc.w, sh.w), 0.0f);
    }
    __shared__ float4 ls[256];
    ls[threadIdx.x] = a;
    __syncthreads();
    for (int off = 128; off >= 16; off >>= 1) {
        if (threadIdx.x < off) {
            float4 b = ls[threadIdx.x + off];
            ls[threadIdx.x].x += b.x;
            ls[threadIdx.x].y += b.y;
            ls[threadIdx.x].z += b.z;
            ls[threadIdx.x].w += b.w;
        }
        __syncthreads();
    }
    if (threadIdx.x < 16) {
        float inv = 1.0f / fmaxf((float)(end - start), 1.0f);
        float4 r = ls[threadIdx.x];
        r.x *= inv; r.y *= inv; r.z *= inv; r.w *= inv;
        ((float4*)pooled)[(size_t)g * 16 + threadIdx.x] = r;
    }
}

// ================= final: proj + L2 normalize; one wave per graph =================
__global__ __launch_bounds__(256) void final_proj(const float* __restrict__ pooled,
                                                  const float* __restrict__ pw,
                                                  const float* __restrict__ pb,
                                                  float* __restrict__ out) {
    __shared__ float sw[64 * 64];
    for (int i = threadIdx.x; i < 4096; i += 256) sw[i] = pw[i];
    __syncthreads();
    int g = blockIdx.x * 4 + (threadIdx.x >> 6);
    int j = threadIdx.x & 63;
    if (g >= N_GRAPHS) return;
    float a = pb[j];
#pragma unroll
    for (int k = 0; k < 64; k++) a = fmaf(pooled[(size_t)g * 64 + k], sw[k * 64 + j], a);
    float ss2 = a * a;
#pragma unroll
    for (int off = 1; off < 64; off <<= 1) ss2 += __shfl_xor(ss2, off);
    out[(size_t)g * 64 + j] = a / fmaxf(sqrtf(ss2), 1e-12f);
}

extern "C" void kernel_launch(void* const* d_in, const int* in_sizes, int n_in,
                              void* d_out, int out_size, void* d_ws, size_t ws_size,
                              hipStream_t stream) {
    const float* x = (const float*)d_in[0];
    const int* eidx = (const int*)d_in[1];
    const int* batch = (const int*)d_in[2];
    const int* src = eidx;
    const int* dst = eidx + N_EDGES;
    const float* W1[3] = {(const float*)d_in[3], (const float*)d_in[9], (const float*)d_in[15]};
    const float* B1[3] = {(const float*)d_in[4], (const float*)d_in[10], (const float*)d_in[16]};
    const float* W2[3] = {(const float*)d_in[5], (const float*)d_in[11], (const float*)d_in[17]};
    const float* B2[3] = {(const float*)d_in[6], (const float*)d_in[12], (const float*)d_in[18]};
    const float* GM[3] = {(const float*)d_in[7], (const float*)d_in[13], (const float*)d_in[19]};
    const float* BT[3] = {(const float*)d_in[8], (const float*)d_in[14], (const float*)d_in[20]};
    const float* PW = (const float*)d_in[21];
    const float* PB = (const float*)d_in[22];
    float* out = (float*)d_out;

    char* ws = (char*)d_ws;
    size_t off = 0;
    auto alloc = [&](size_t bytes) -> void* {
        void* p = ws + off;
        off += (bytes + 255) & ~(size_t)255;
        return p;
    };
    float* A    = (float*)alloc((size_t)N_NODES * 64 * 4);   // h2 (fp32, stats source)
    __half* A16 = (__half*)alloc((size_t)N_NODES * 64 * 2);  // h2 (fp16, gather/pool operand)
    float* C    = (float*)alloc((size_t)N_NODES * 64 * 4);   // agg buffer
    float* agg0 = (float*)alloc((size_t)N_NODES * 7 * 4);
    float* x8   = (float*)alloc((size_t)N_NODES * 8 * 4);
    int* cnt    = (int*)alloc((size_t)N_NODES * 4);
    int* rowptr = (int*)alloc((size_t)N_NODES * 4);
    int* elist  = (int*)alloc((size_t)N_EDGES * 4);
    int* ebuf   = (int*)alloc((size_t)N_EDGES * 4);   // packed (dlo<<17)|src
    int* hist_g = (int*)alloc((size_t)MS_N * 4);
    int* hist_s = (int*)alloc((size_t)MS_N * 4);
    int* msum   = (int*)alloc((size_t)MS_SBLK * 4);
    int* bptr   = (int*)alloc((size_t)(NBUCK + 1) * 4);
    int* grow   = (int*)alloc(1025 * 4);
    double* acc = (double*)alloc(3 * 128 * sizeof(double));
    float* ss0    = (float*)alloc(128 * 4);
    float* ss1    = (float*)alloc(128 * 4);
    float* ss2    = (float*)alloc(128 * 4);
    float* pooled = (float*)alloc((size_t)N_GRAPHS * 64 * 4);

    hipMemsetAsync(acc, 0, 3 * 128 * sizeof(double), stream);

    const int row_grid = (N_NODES + 255) / 256;        // 391
    const int g7_grid = (N_NODES * 8 + 255) / 256;     // 3125
    const int g64_grid = (N_NODES * 16 + 255) / 256;   // 6250 (16 lanes per node)

    // ---- deterministic multi-split CSR build (reused by all 3 layers) ----
    msplit_hist<<<NB, 256, 0, stream>>>(dst, hist_g);
    ms_scan_blocks<<<MS_SBLK, 256, 0, stream>>>(hist_g, hist_s, msum);
    ms_scan_sums<<<1, 64, 0, stream>>>(msum);
    ms_scan_apply<<<(MS_N + 255) / 256, 256, 0, stream>>>(hist_s, msum, bptr);
    msplit_place<<<NB, 256, 0, stream>>>(src, dst, hist_s, ebuf);
    bucket_csr<<<NBUCK, 256, 0, stream>>>(ebuf, bptr, rowptr, cnt, elist);
    gbounds<<<5, 256, 0, stream>>>(batch, grow);
    pad8<<<g7_grid, 256, 0, stream>>>(x, x8);

    // ---- layer 0 ----
    gather7<<<g7_grid, 256, 0, stream>>>(x8, rowptr, cnt, elist, agg0);
    mlp_kernel<7><<<row_grid, 256, 0, stream>>>(agg0, W1[0], B1[0], W2[0], B2[0], A);
    bn_stats<<<row_grid, 256, 0, stream>>>(A, acc, A16);
    bn_finalize<<<1, 64, 0, stream>>>(acc, GM[0], BT[0], ss0);

    // ---- layer 1 (BN+relu of layer 0 fused into fp16 gather) ----
    gather64_bn<<<g64_grid, 256, 0, stream>>>(A16, ss0, rowptr, cnt, elist, C);
    mlp_kernel<64><<<row_grid, 256, 0, stream>>>(C, W1[1], B1[1], W2[1], B2[1], A);
    bn_stats<<<row_grid, 256, 0, stream>>>(A, acc + 128, A16);
    bn_finalize<<<1, 64, 0, stream>>>(acc + 128, GM[1], BT[1], ss1);

    // ---- layer 2 ----
    gather64_bn<<<g64_grid, 256, 0, stream>>>(A16, ss1, rowptr, cnt, elist, C);
    mlp_kernel<64><<<row_grid, 256, 0, stream>>>(C, W1[2], B1[2], W2[2], B2[2], A);
    bn_stats<<<row_grid, 256, 0, stream>>>(A, acc + 256, A16);
    bn_finalize<<<1, 64, 0, stream>>>(acc + 256, GM[2], BT[2], ss2);

    // ---- pool (BN+relu fused, fp16 input, deterministic per-graph reduction) ----
    pool_bn<<<N_GRAPHS, 256, 0, stream>>>(A16, ss2, grow, pooled);

    // ---- readout ----
    final_proj<<<N_GRAPHS / 4, 256, 0, stream>>>(pooled, PW, PB, out);
}